// Round 3
// baseline (7598.211 us; speedup 1.0000x reference)
//
#include <hip/hip_runtime.h>

#define N_TOT 65536
#define C_DIM 128
#define K_CB  1024
#define BN 64
#define BK 32
#define LDZ 132   // padded LDS row stride (floats)
#define LDC 132
#define NROW_B 4
#define NBLK_B (N_TOT / NROW_B)

// ---------------------------------------------------------------------------
// Kernel 1: row squared-norms in fp64, stored as correctly-rounded fp32.
// (ze_sq errors are a common per-row shift on a uniform fp32 grid -> argmin-
//  invariant; cb_sq ulp is ~3.7e-9 << key quantum 1.5e-5 -> safe.)
// One wave per row: 64 lanes x float2 = 128 dims.
// ---------------------------------------------------------------------------
__global__ __launch_bounds__(256) void sqnorm_kernel(const float* __restrict__ x,
                                                     float* __restrict__ out,
                                                     int nrows) {
  int w = threadIdx.x >> 6, lane = threadIdx.x & 63;
  int r = blockIdx.x * 4 + w;
  if (r >= nrows) return;
  float2 v = reinterpret_cast<const float2*>(x + (size_t)r * C_DIM)[lane];
  double s = (double)v.x * (double)v.x + (double)v.y * (double)v.y;
#pragma unroll
  for (int off = 32; off >= 1; off >>= 1) s += __shfl_xor(s, off, 64);
  if (lane == 0) out[r] = (float)s;
}

// ---------------------------------------------------------------------------
// Kernel 2: fp32 distance pass, per-row TOP-4 candidate selection.
// 16x16 threads; 64-row tile x full C=128; K in chunks of 32 codes.
// Ranking key = cb_sq - 2*dot (ze_sq omitted: common shift). fp32 noise
// ~2e-7 vs top-4 margin -> P(np's pick outside top-4) ~ 1e-11.
// ---------------------------------------------------------------------------
__global__ __launch_bounds__(256) void dist_topk_kernel(
    const float* __restrict__ ze, const float* __restrict__ cb,
    const float* __restrict__ cbsq, ushort* __restrict__ cand) {
  __shared__ float zeS[BN][LDZ];   // 33792 B
  __shared__ float cbS[BK][LDC];   // 16896 B (aliased as reduce scratch at end)

  const int tx = threadIdx.x, ty = threadIdx.y;
  const int tid = ty * 16 + tx;
  const int rowbase = blockIdx.x * BN;

#pragma unroll
  for (int i = 0; i < 8; ++i) {
    int fid = i * 256 + tid;
    int row = fid >> 5, c4 = fid & 31;
    float4 v = reinterpret_cast<const float4*>(ze)[(size_t)(rowbase + row) * 32 + c4];
    *reinterpret_cast<float4*>(&zeS[row][c4 * 4]) = v;
  }

  float b1k[4], b2k[4];
  int b1i[4], b2i[4];
#pragma unroll
  for (int r = 0; r < 4; ++r) { b1k[r] = 3e38f; b2k[r] = 3e38f; b1i[r] = 0; b2i[r] = 0; }

  for (int kc = 0; kc < K_CB / BK; ++kc) {
    __syncthreads();
#pragma unroll
    for (int i = 0; i < 4; ++i) {
      int fid = i * 256 + tid;
      int code = fid >> 5, c4 = fid & 31;
      float4 v = reinterpret_cast<const float4*>(cb)[(size_t)(kc * BK + code) * 32 + c4];
      *reinterpret_cast<float4*>(&cbS[code][c4 * 4]) = v;
    }
    __syncthreads();

    float acc[4][2];
#pragma unroll
    for (int r = 0; r < 4; ++r) { acc[r][0] = 0.f; acc[r][1] = 0.f; }
#pragma unroll
    for (int c2 = 0; c2 < 64; ++c2) {
      int c = c2 * 2;
      float2 b0 = *reinterpret_cast<const float2*>(&cbS[tx][c]);
      float2 b1 = *reinterpret_cast<const float2*>(&cbS[tx + 16][c]);
#pragma unroll
      for (int r = 0; r < 4; ++r) {
        float2 z = *reinterpret_cast<const float2*>(&zeS[ty * 4 + r][c]);
        acc[r][0] = fmaf(z.x, b0.x, acc[r][0]);
        acc[r][0] = fmaf(z.y, b0.y, acc[r][0]);
        acc[r][1] = fmaf(z.x, b1.x, acc[r][1]);
        acc[r][1] = fmaf(z.y, b1.y, acc[r][1]);
      }
    }

    float cs0 = cbsq[kc * BK + tx];
    float cs1 = cbsq[kc * BK + tx + 16];
#pragma unroll
    for (int r = 0; r < 4; ++r) {
      float k0 = fmaf(-2.f, acc[r][0], cs0);
      int i0 = kc * BK + tx;
      if (k0 < b2k[r]) {
        if (k0 < b1k[r]) { b2k[r] = b1k[r]; b2i[r] = b1i[r]; b1k[r] = k0; b1i[r] = i0; }
        else             { b2k[r] = k0; b2i[r] = i0; }
      }
      float k1 = fmaf(-2.f, acc[r][1], cs1);
      int i1 = kc * BK + tx + 16;
      if (k1 < b2k[r]) {
        if (k1 < b1k[r]) { b2k[r] = b1k[r]; b2i[r] = b1i[r]; b1k[r] = k1; b1i[r] = i1; }
        else             { b2k[r] = k1; b2i[r] = i1; }
      }
    }
  }

  __syncthreads();
  float (*sKey)[32] = reinterpret_cast<float(*)[32]>(&cbS[0][0]);
  int (*sIdx)[32] = reinterpret_cast<int(*)[32]>(
      reinterpret_cast<char*>(&cbS[0][0]) + BN * 32 * sizeof(float));
#pragma unroll
  for (int r = 0; r < 4; ++r) {
    int row = ty * 4 + r;
    sKey[row][tx * 2] = b1k[r];     sIdx[row][tx * 2] = b1i[r];
    sKey[row][tx * 2 + 1] = b2k[r]; sIdx[row][tx * 2 + 1] = b2i[r];
  }
  __syncthreads();
  if (tid < BN) {
    int row = tid;
    float k4[4] = {3e38f, 3e38f, 3e38f, 3e38f};
    int i4[4] = {0, 0, 0, 0};
    for (int t = 0; t < 32; ++t) {
      float v = sKey[row][t];
      int ii = sIdx[row][t];
      if (v < k4[3]) {
        int p = 3;
        while (p > 0 && v < k4[p - 1]) { k4[p] = k4[p - 1]; i4[p] = i4[p - 1]; --p; }
        k4[p] = v; i4[p] = ii;
      }
    }
    ushort4 c;
    c.x = (ushort)i4[0]; c.y = (ushort)i4[1]; c.z = (ushort)i4[2]; c.w = (ushort)i4[3];
    reinterpret_cast<ushort4*>(cand)[rowbase + row] = c;
  }
}

// ---------------------------------------------------------------------------
// Kernel 3: candidate rescore REPLICATING the numpy fp32 key:
//   key = fl32( fl32( ze_sq32 - fl32(2*cross_exact) ) + cb_sq32 )
// cross in fp64 (fp32xfp32 products exact in fp64). Ties (equal fp32 keys,
// common after quantization at ulp(128)) -> lowest index = np first-occurrence.
// Winner: gather z_q + fp64 loss partial. One wave per row.
// ---------------------------------------------------------------------------
__global__ __launch_bounds__(256) void rescore_kernel(
    const float* __restrict__ ze, const float* __restrict__ cb,
    const float* __restrict__ zesq, const float* __restrict__ cbsq,
    const ushort* __restrict__ cand, float* __restrict__ zq,
    float* __restrict__ idx_f, double* __restrict__ partial) {
  int w = threadIdx.x >> 6, lane = threadIdx.x & 63;
  int row = blockIdx.x * NROW_B + w;
  ushort4 c4 = reinterpret_cast<const ushort4*>(cand)[row];
  int ci[4] = {c4.x, c4.y, c4.z, c4.w};
  float2 z = reinterpret_cast<const float2*>(ze)[(size_t)row * 64 + lane];
  float zs = zesq[row];

  float best = 3.4e38f;
  int bidx = K_CB + 1;
  float2 bc = make_float2(0.f, 0.f);
#pragma unroll
  for (int j = 0; j < 4; ++j) {
    float2 c = reinterpret_cast<const float2*>(cb)[(size_t)ci[j] * 64 + lane];
    double p = (double)z.x * (double)c.x + (double)z.y * (double)c.y;
#pragma unroll
    for (int off = 32; off >= 1; off >>= 1) p += __shfl_xor(p, off, 64);
    // numpy fp32 rounding chain (no fusable mul+add patterns -> exact IEEE):
    float t = (float)(2.0 * p);       // fl32(2*cross)
    float u = zs - t;                 // fl32(ze_sq - t)
    float d = u + cbsq[ci[j]];        // fl32(u + cb_sq)
    if (d < best || (d == best && ci[j] < bidx)) { best = d; bidx = ci[j]; bc = c; }
  }

  reinterpret_cast<float2*>(zq)[(size_t)row * 64 + lane] = bc;

  double dx = (double)z.x - (double)bc.x;
  double dy = (double)z.y - (double)bc.y;
  double l = dx * dx + dy * dy;
#pragma unroll
  for (int off = 32; off >= 1; off >>= 1) l += __shfl_xor(l, off, 64);

  __shared__ double sh[NROW_B];
  if (lane == 0) { idx_f[row] = (float)bidx; sh[w] = l; }
  __syncthreads();
  if (threadIdx.x == 0) partial[blockIdx.x] = sh[0] + sh[1] + sh[2] + sh[3];
}

__global__ __launch_bounds__(256) void finalize_kernel(
    const double* __restrict__ partial, float* __restrict__ out_loss) {
  double s = 0.0;
  for (int i = threadIdx.x; i < NBLK_B; i += 256) s += partial[i];
#pragma unroll
  for (int off = 32; off >= 1; off >>= 1) s += __shfl_down(s, off, 64);
  __shared__ double sh[4];
  int wv = threadIdx.x >> 6, lane = threadIdx.x & 63;
  if (lane == 0) sh[wv] = s;
  __syncthreads();
  if (threadIdx.x == 0) {
    double tot = sh[0] + sh[1] + sh[2] + sh[3];
    double mse = tot / (double)((size_t)N_TOT * C_DIM);
    *out_loss = (float)(1.75 * mse);  // 0.75*q_latent + e_latent, both == mse
  }
}

// ---------------------------------------------------------------------------
extern "C" void kernel_launch(void* const* d_in, const int* in_sizes, int n_in,
                              void* d_out, int out_size, void* d_ws, size_t ws_size,
                              hipStream_t stream) {
  const float* ze = (const float*)d_in[0];
  const float* cb = (const float*)d_in[1];

  float* out = (float*)d_out;
  float* zq = out;                                   // [N*C]
  float* out_loss = out + (size_t)N_TOT * C_DIM;     // [1]
  float* idx_f = out_loss + 1;                       // [N]

  // ws: cbsq fp32 [0,4K) | zesq fp32 [4K, 4K+256K) | cand ushort4 [266240, +512K)
  //     | partial double [790528, +128K). Total ~900 KB.
  float* cbsq = (float*)d_ws;
  float* zesq = (float*)((char*)d_ws + 4096);
  ushort* cand = (ushort*)((char*)d_ws + 266240);
  double* partial = (double*)((char*)d_ws + 790528);

  sqnorm_kernel<<<K_CB / 4, 256, 0, stream>>>(cb, cbsq, K_CB);
  sqnorm_kernel<<<N_TOT / 4, 256, 0, stream>>>(ze, zesq, N_TOT);
  dist_topk_kernel<<<N_TOT / BN, dim3(16, 16), 0, stream>>>(ze, cb, cbsq, cand);
  rescore_kernel<<<NBLK_B, 256, 0, stream>>>(ze, cb, zesq, cbsq, cand, zq, idx_f, partial);
  finalize_kernel<<<1, 256, 0, stream>>>(partial, out_loss);
}

// Round 4
// 432.508 us; speedup vs baseline: 17.5678x; 17.5678x over previous
//
#include <hip/hip_runtime.h>

#define N_TOT 65536
#define C_DIM 128
#define K_CB  1024
#define BN 64
#define BK 64
#define LDZ 132   // padded LDS row stride (floats): bank stride 4 -> <=2-way (free)
#define LDC 132
#define NROW_B 4
#define NBLK_B (N_TOT / NROW_B)

// ---------------------------------------------------------------------------
// Kernel 1: row squared-norms in fp64, stored as correctly-rounded fp32.
// One wave per row: 64 lanes x float2 = 128 dims.
// ---------------------------------------------------------------------------
__global__ __launch_bounds__(256) void sqnorm_kernel(const float* __restrict__ x,
                                                     float* __restrict__ out,
                                                     int nrows) {
  int w = threadIdx.x >> 6, lane = threadIdx.x & 63;
  int r = blockIdx.x * 4 + w;
  if (r >= nrows) return;
  float2 v = reinterpret_cast<const float2*>(x + (size_t)r * C_DIM)[lane];
  double s = (double)v.x * (double)v.x + (double)v.y * (double)v.y;
#pragma unroll
  for (int off = 32; off >= 1; off >>= 1) s += __shfl_xor(s, off, 64);
  if (lane == 0) out[r] = (float)s;
}

// ---------------------------------------------------------------------------
// Kernel 2: fp32 filter pass, per-row TOP-4 candidates.
// 16x16 threads; tile 64 rows x C=128; K in chunks of 64 codes.
// Per thread: 4 rows x 4 codes (tx+16j); float4 LDS reads; unroll 4 ONLY
// (full unroll caused the R3 spill disaster: 21 GB scratch traffic).
// ---------------------------------------------------------------------------
__global__ __launch_bounds__(256, 2) void dist_topk_kernel(
    const float* __restrict__ ze, const float* __restrict__ cb,
    const float* __restrict__ cbsq, ushort* __restrict__ cand) {
  __shared__ float zeS[BN][LDZ];      // 33792 B
  __shared__ float cbS[BK][LDC];      // 33792 B (aliased as reduce scratch at end)
  __shared__ float cbsqS[K_CB];       // 4096 B

  const int tx = threadIdx.x, ty = threadIdx.y;
  const int tid = ty * 16 + tx;
  const int rowbase = blockIdx.x * BN;

  // Stage z_e tile (64 rows x 32 float4) + cbsq (256 float4), coalesced.
#pragma unroll
  for (int i = 0; i < 8; ++i) {
    int fid = i * 256 + tid;
    int row = fid >> 5, c4 = fid & 31;
    float4 v = reinterpret_cast<const float4*>(ze)[(size_t)(rowbase + row) * 32 + c4];
    *reinterpret_cast<float4*>(&zeS[row][c4 * 4]) = v;
  }
  reinterpret_cast<float4*>(cbsqS)[tid] = reinterpret_cast<const float4*>(cbsq)[tid];

  float b1k[4], b2k[4];
  int b1i[4], b2i[4];
#pragma unroll
  for (int r = 0; r < 4; ++r) { b1k[r] = 3e38f; b2k[r] = 3e38f; b1i[r] = 0; b2i[r] = 0; }

  for (int kc = 0; kc < K_CB / BK; ++kc) {
    __syncthreads();  // protects cbS (prev readers) and, first time, cbsqS/zeS
#pragma unroll
    for (int i = 0; i < 8; ++i) {
      int fid = i * 256 + tid;
      int code = fid >> 5, c4 = fid & 31;
      float4 v = reinterpret_cast<const float4*>(cb)[(size_t)(kc * BK + code) * 32 + c4];
      *reinterpret_cast<float4*>(&cbS[code][c4 * 4]) = v;
    }
    __syncthreads();

    float acc[4][4];
#pragma unroll
    for (int r = 0; r < 4; ++r)
#pragma unroll
      for (int j = 0; j < 4; ++j) acc[r][j] = 0.f;

#pragma unroll 4
    for (int c4 = 0; c4 < 32; ++c4) {
      const int cc = c4 * 4;
      float4 b[4], z[4];
#pragma unroll
      for (int j = 0; j < 4; ++j) b[j] = *reinterpret_cast<const float4*>(&cbS[tx + 16 * j][cc]);
#pragma unroll
      for (int r = 0; r < 4; ++r) z[r] = *reinterpret_cast<const float4*>(&zeS[ty * 4 + r][cc]);
#pragma unroll
      for (int r = 0; r < 4; ++r)
#pragma unroll
        for (int j = 0; j < 4; ++j) {
          acc[r][j] = fmaf(z[r].x, b[j].x, acc[r][j]);
          acc[r][j] = fmaf(z[r].y, b[j].y, acc[r][j]);
          acc[r][j] = fmaf(z[r].z, b[j].z, acc[r][j]);
          acc[r][j] = fmaf(z[r].w, b[j].w, acc[r][j]);
        }
    }

#pragma unroll
    for (int j = 0; j < 4; ++j) {
      float cs = cbsqS[kc * BK + tx + 16 * j];
      int idx = kc * BK + tx + 16 * j;
#pragma unroll
      for (int r = 0; r < 4; ++r) {
        float k = fmaf(-2.f, acc[r][j], cs);
        if (k < b2k[r]) {
          if (k < b1k[r]) { b2k[r] = b1k[r]; b2i[r] = b1i[r]; b1k[r] = k; b1i[r] = idx; }
          else            { b2k[r] = k; b2i[r] = idx; }
        }
      }
    }
  }

  // Per-row top-4 of the 32 distinct per-thread candidates (alias cbS).
  __syncthreads();
  float (*sKey)[32] = reinterpret_cast<float(*)[32]>(&cbS[0][0]);
  int (*sIdx)[32] = reinterpret_cast<int(*)[32]>(
      reinterpret_cast<char*>(&cbS[0][0]) + BN * 32 * sizeof(float));
#pragma unroll
  for (int r = 0; r < 4; ++r) {
    int row = ty * 4 + r;
    sKey[row][tx * 2] = b1k[r];     sIdx[row][tx * 2] = b1i[r];
    sKey[row][tx * 2 + 1] = b2k[r]; sIdx[row][tx * 2 + 1] = b2i[r];
  }
  __syncthreads();
  if (tid < BN) {
    int row = tid;
    float k0 = 3e38f, k1 = 3e38f, k2 = 3e38f, k3 = 3e38f;
    int i0 = 0, i1 = 0, i2 = 0, i3 = 0;
    for (int t = 0; t < 32; ++t) {
      float v = sKey[row][t];
      int ii = sIdx[row][t];
      if (v < k3) {
        if (v < k2) {
          k3 = k2; i3 = i2;
          if (v < k1) {
            k2 = k1; i2 = i1;
            if (v < k0) { k1 = k0; i1 = i0; k0 = v; i0 = ii; }
            else        { k1 = v; i1 = ii; }
          } else { k2 = v; i2 = ii; }
        } else { k3 = v; i3 = ii; }
      }
    }
    ushort4 c;
    c.x = (ushort)i0; c.y = (ushort)i1; c.z = (ushort)i2; c.w = (ushort)i3;
    reinterpret_cast<ushort4*>(cand)[rowbase + row] = c;
  }
}

// ---------------------------------------------------------------------------
// Kernel 3: candidate rescore REPLICATING the numpy fp32 key:
//   key = fl32( fl32( ze_sq32 - fl32(2*cross_exact) ) + cb_sq32 )
// Ties -> lowest index (np first-occurrence). Winner: z_q + fp64 loss partial.
// FROZEN from Round 3 (verified: all 65536 indices matched).
// ---------------------------------------------------------------------------
__global__ __launch_bounds__(256) void rescore_kernel(
    const float* __restrict__ ze, const float* __restrict__ cb,
    const float* __restrict__ zesq, const float* __restrict__ cbsq,
    const ushort* __restrict__ cand, float* __restrict__ zq,
    float* __restrict__ idx_f, double* __restrict__ partial) {
  int w = threadIdx.x >> 6, lane = threadIdx.x & 63;
  int row = blockIdx.x * NROW_B + w;
  ushort4 c4 = reinterpret_cast<const ushort4*>(cand)[row];
  int ci[4] = {c4.x, c4.y, c4.z, c4.w};
  float2 z = reinterpret_cast<const float2*>(ze)[(size_t)row * 64 + lane];
  float zs = zesq[row];

  float best = 3.4e38f;
  int bidx = K_CB + 1;
  float2 bc = make_float2(0.f, 0.f);
#pragma unroll
  for (int j = 0; j < 4; ++j) {
    float2 c = reinterpret_cast<const float2*>(cb)[(size_t)ci[j] * 64 + lane];
    double p = (double)z.x * (double)c.x + (double)z.y * (double)c.y;
#pragma unroll
    for (int off = 32; off >= 1; off >>= 1) p += __shfl_xor(p, off, 64);
    float t = (float)(2.0 * p);       // fl32(2*cross)
    float u = zs - t;                 // fl32(ze_sq - t)
    float d = u + cbsq[ci[j]];        // fl32(u + cb_sq)
    if (d < best || (d == best && ci[j] < bidx)) { best = d; bidx = ci[j]; bc = c; }
  }

  reinterpret_cast<float2*>(zq)[(size_t)row * 64 + lane] = bc;

  double dx = (double)z.x - (double)bc.x;
  double dy = (double)z.y - (double)bc.y;
  double l = dx * dx + dy * dy;
#pragma unroll
  for (int off = 32; off >= 1; off >>= 1) l += __shfl_xor(l, off, 64);

  __shared__ double sh[NROW_B];
  if (lane == 0) { idx_f[row] = (float)bidx; sh[w] = l; }
  __syncthreads();
  if (threadIdx.x == 0) partial[blockIdx.x] = sh[0] + sh[1] + sh[2] + sh[3];
}

__global__ __launch_bounds__(256) void finalize_kernel(
    const double* __restrict__ partial, float* __restrict__ out_loss) {
  double s = 0.0;
  for (int i = threadIdx.x; i < NBLK_B; i += 256) s += partial[i];
#pragma unroll
  for (int off = 32; off >= 1; off >>= 1) s += __shfl_down(s, off, 64);
  __shared__ double sh[4];
  int wv = threadIdx.x >> 6, lane = threadIdx.x & 63;
  if (lane == 0) sh[wv] = s;
  __syncthreads();
  if (threadIdx.x == 0) {
    double tot = sh[0] + sh[1] + sh[2] + sh[3];
    double mse = tot / (double)((size_t)N_TOT * C_DIM);
    *out_loss = (float)(1.75 * mse);  // 0.75*q_latent + e_latent, both == mse
  }
}

// ---------------------------------------------------------------------------
extern "C" void kernel_launch(void* const* d_in, const int* in_sizes, int n_in,
                              void* d_out, int out_size, void* d_ws, size_t ws_size,
                              hipStream_t stream) {
  const float* ze = (const float*)d_in[0];
  const float* cb = (const float*)d_in[1];

  float* out = (float*)d_out;
  float* zq = out;                                   // [N*C]
  float* out_loss = out + (size_t)N_TOT * C_DIM;     // [1]
  float* idx_f = out_loss + 1;                       // [N]

  float* cbsq = (float*)d_ws;                             // 4 KB
  float* zesq = (float*)((char*)d_ws + 4096);             // 256 KB
  ushort* cand = (ushort*)((char*)d_ws + 266240);         // 512 KB
  double* partial = (double*)((char*)d_ws + 790528);      // 128 KB

  sqnorm_kernel<<<K_CB / 4, 256, 0, stream>>>(cb, cbsq, K_CB);
  sqnorm_kernel<<<N_TOT / 4, 256, 0, stream>>>(ze, zesq, N_TOT);
  dist_topk_kernel<<<N_TOT / BN, dim3(16, 16), 0, stream>>>(ze, cb, cbsq, cand);
  rescore_kernel<<<NBLK_B, 256, 0, stream>>>(ze, cb, zesq, cbsq, cand, zq, idx_f, partial);
  finalize_kernel<<<1, 256, 0, stream>>>(partial, out_loss);
}